// Round 11
// baseline (151.041 us; speedup 1.0000x reference)
//
#include <hip/hip_runtime.h>

// Tropical (max-times) matmul: out[i,k] = max_j sigmoid(A[j,k]) * x[i,j]
// x: [2048, 256] f32   A: [256, 512] f32   out: [2048, 512] f32
//
// Round 11: DECOMPOSITION ROUND. R6-R10 (five disjoint structures) all land
// 23-25us; marginal dispatch cost measured ~0 (R9 vs R10). Hypothesis:
// dur_us = per-replay fixed overhead (~15us) + kernel (~8us). This round
// launches the identical R10 kernel 8x in one graph (deterministic: same
// inputs -> same output). k = (R11_dur - R10_dur)/7 decomposes the two.
// Kernel body is byte-identical to R10 (known correct, absmax 0.031).

typedef _Float16 h1;
typedef __attribute__((ext_vector_type(2))) _Float16 h2v;
typedef __attribute__((ext_vector_type(4))) float f4;

constexpr int JD   = 256;
constexpr int KD   = 512;
constexpr int BI   = 32;    // rows per block
constexpr int KW   = 64;    // k per block
constexpr int TI   = 8;     // rows per wave
constexpr int LSTR = 132;   // LDS row stride in h2v (528B, 16B-aligned)
constexpr int NCH  = 16;    // chunks of 8 pairs (16 j)

__device__ __forceinline__ float sigmoidf_fast(float a) {
    return 1.0f / (1.0f + __expf(-a));
}

__global__ __launch_bounds__(256) void tropical_fused(
        const float* __restrict__ x,
        const float* __restrict__ A,
        float* __restrict__ out) {
    __shared__ h2v xl[BI * LSTR];   // 16896 B: [row][pair]
    __shared__ h2v Wl[KW * LSTR];   // 33792 B: [k_local][pair]

    const int t  = (int)threadIdx.x;
    const int kg = (int)blockIdx.x & 7;    // 8 k-groups of 64
    const int ib = (int)blockIdx.x >> 3;   // 64 i-blocks of 32
    const int i0 = ib * BI;
    const int k0 = kg * KW;

    // ---- phase 1a: stage x slab -> fp16 pairs ----
    {
        const int srow = t >> 3;           // 0..31
        const int c0   = (t & 7) * 32;     // float col base
        const float* xs = x + (i0 + srow) * JD + c0;
        #pragma unroll
        for (int q = 0; q < 4; ++q) {      // 8 floats -> 4 h2v -> 1 b128 each
            const f4 v0 = ((const f4*)xs)[2 * q];
            const f4 v1 = ((const f4*)xs)[2 * q + 1];
            union { f4 v; h2v h[4]; } u;
            u.h[0] = h2v{(h1)v0.x, (h1)v0.y};
            u.h[1] = h2v{(h1)v0.z, (h1)v0.w};
            u.h[2] = h2v{(h1)v1.x, (h1)v1.y};
            u.h[3] = h2v{(h1)v1.z, (h1)v1.w};
            *(f4*)&xl[srow * LSTR + c0 / 2 + q * 4] = u.v;
        }
    }

    // ---- phase 1b: stage W slab, sigmoid on the fly ----
    {
        const int kl = t & 63;             // k_local
        const int j0 = (t >> 6) * 64;      // 4 thread-groups x 64 j
        const float* Ak = A + k0 + kl;
        #pragma unroll 1
        for (int pass = 0; pass < 4; ++pass) {
            const int jb = j0 + pass * 16;
            float s[16];
            #pragma unroll
            for (int m = 0; m < 16; ++m)   // coalesced dword loads
                s[m] = Ak[(jb + m) * KD];
            union { f4 v; h2v h[4]; } u0, u1;
            #pragma unroll
            for (int m = 0; m < 4; ++m)
                u0.h[m] = h2v{(h1)sigmoidf_fast(s[2 * m]),
                              (h1)sigmoidf_fast(s[2 * m + 1])};
            #pragma unroll
            for (int m = 0; m < 4; ++m)
                u1.h[m] = h2v{(h1)sigmoidf_fast(s[8 + 2 * m]),
                              (h1)sigmoidf_fast(s[9 + 2 * m])};
            *(f4*)&Wl[kl * LSTR + jb / 2]     = u0.v;
            *(f4*)&Wl[kl * LSTR + jb / 2 + 4] = u1.v;
        }
    }
    __syncthreads();

    // ---- phase 2: barrier-free ping-pong compute ----
    const int lane = t & 63;
    const int wv   = __builtin_amdgcn_readfirstlane(t >> 6);
    const int r0   = wv * TI;

    h2v acc[TI];
    #pragma unroll
    for (int r = 0; r < TI; ++r)
        acc[r] = h2v{(h1)(-65504.0f), (h1)(-65504.0f)};

    f4 XA[TI][2], XB[TI][2];
    f4 WA[2], WB[2];

    auto loadX = [&](f4 (&X)[TI][2], int c) {
        #pragma unroll
        for (int r = 0; r < TI; ++r) {
            X[r][0] = *(const f4*)&xl[(r0 + r) * LSTR + c * 8];
            X[r][1] = *(const f4*)&xl[(r0 + r) * LSTR + c * 8 + 4];
        }
    };
    auto loadW = [&](f4 (&W)[2], int c) {
        W[0] = *(const f4*)&Wl[lane * LSTR + c * 8];
        W[1] = *(const f4*)&Wl[lane * LSTR + c * 8 + 4];
    };
    auto compute = [&](const f4 (&X)[TI][2], const f4 (&W)[2]) {
        #pragma unroll
        for (int r = 0; r < TI; ++r) {
            #pragma unroll
            for (int hf = 0; hf < 2; ++hf) {
                union { f4 v; h2v h[4]; } ux, uw;
                ux.v = X[r][hf];
                uw.v = W[hf];
                #pragma unroll
                for (int q = 0; q < 4; ++q)
                    acc[r] = __builtin_elementwise_max(acc[r],
                                                       ux.h[q] * uw.h[q]);
            }
        }
    };

    loadX(XA, 0);
    loadW(WA, 0);

    #pragma unroll 1
    for (int c = 0; c < NCH; c += 2) {
        loadX(XB, c + 1);              // NCH even: c+1 always valid
        loadW(WB, c + 1);
        compute(XA, WA);
        if (c + 2 < NCH) {
            loadX(XA, c + 2);
            loadW(WA, c + 2);
        }
        compute(XB, WB);
    }

    // ---- epilogue: fold pair halves, coalesced f32 stores ----
    #pragma unroll
    for (int r = 0; r < TI; ++r)
        out[(i0 + r0 + r) * KD + k0 + lane] =
            fmaxf((float)acc[r][0], (float)acc[r][1]);
}

extern "C" void kernel_launch(void* const* d_in, const int* in_sizes, int n_in,
                              void* d_out, int out_size, void* d_ws, size_t ws_size,
                              hipStream_t stream) {
    const float* x = (const float*)d_in[0];
    const float* A = (const float*)d_in[1];
    float* out = (float*)d_out;

    // DECOMPOSITION: 8 identical launches (same inputs -> same output each
    // time; fully deterministic). k = (dur_R11 - dur_R10) / 7.
    for (int rep = 0; rep < 8; ++rep) {
        hipLaunchKernelGGL(tropical_fused, dim3(512), dim3(256), 0, stream,
                           x, A, out);
    }
}

// Round 12
// 28.249 us; speedup vs baseline: 5.3469x; 5.3469x over previous
//
#include <hip/hip_runtime.h>

// Tropical (max-times) matmul: out[i,k] = max_j sigmoid(A[j,k]) * x[i,j]
// x: [2048, 256] f32   A: [256, 512] f32   out: [2048, 512] f32
//
// Round 12: LDS-cycle-optimal register blocking. R11 decomposition proved
// kernel ~18.3us / overhead ~4.8us, and the 18us matches the LDS-pipe
// model: b128-reads/wave = 32*(TI+TK), cycles/CU = 24576*(1/TI+1/TK).
// R10 was TI=8,TK=1 (factor 1.125). This round: TI=TK=4 (factor 0.5).
//  - wave = 4 rows x 256 k (lane owns 4 contiguous k), block = 4 waves
//    = 16 rows x 256 k, grid = 256 = 1 block/CU.
//  - W slab in LDS as [pair][k_local] (128 KB, sigmoid on the fly):
//    lane reads Wl[p][4l..4l+3] b128 -> 64 lanes cover one 1KB row,
//    perfectly conflict-free. x slab [row][pair] (8 KB), uniform b128.
//  - Inner: v_pk_mul_f16 + v_pk_max_f16; acc[4][4] h2v.
//  - LDS/CU ~12.3k cyc (5.1us), VALU/SIMD ~8.2k cyc (3.4us) - balanced.

typedef _Float16 h1;
typedef __attribute__((ext_vector_type(2))) _Float16 h2v;
typedef __attribute__((ext_vector_type(4))) float f4;

constexpr int JD    = 256;
constexpr int KD    = 512;
constexpr int BI    = 16;     // rows per block
constexpr int KW    = 256;    // k per block
constexpr int TI    = 4;      // rows per wave
constexpr int TK    = 4;      // k per lane
constexpr int NPAIR = 128;    // j-pairs
constexpr int NCH   = 16;     // chunks of 8 pairs (16 j)

__device__ __forceinline__ float sigmoidf_fast(float a) {
    return 1.0f / (1.0f + __expf(-a));
}

__global__ __launch_bounds__(256) void tropical_fused(
        const float* __restrict__ x,
        const float* __restrict__ A,
        float* __restrict__ out) {
    __shared__ h2v Wl[NPAIR][KW];   // 131072 B: [pair][k_local]
    __shared__ h2v xl[BI][NPAIR];   //   8192 B: [row][pair]

    const int t  = (int)threadIdx.x;
    const int ks = (int)blockIdx.x & 1;     // 2 k-slabs of 256
    const int ib = (int)blockIdx.x >> 1;    // 128 i-blocks of 16
    const int i0 = ib * BI;
    const int k0 = ks * KW;

    // ---- phase 1a: stage x slab -> fp16 pairs [row][pair] ----
    {
        const int srow = t >> 4;            // 0..15
        const int c0   = (t & 15) * 16;     // float col base
        const float* xs = x + (i0 + srow) * JD + c0;
        const f4 v0 = ((const f4*)xs)[0];
        const f4 v1 = ((const f4*)xs)[1];
        const f4 v2 = ((const f4*)xs)[2];
        const f4 v3 = ((const f4*)xs)[3];
        union { f4 v; h2v h[4]; } u0, u1;
        u0.h[0] = h2v{(h1)v0.x, (h1)v0.y};
        u0.h[1] = h2v{(h1)v0.z, (h1)v0.w};
        u0.h[2] = h2v{(h1)v1.x, (h1)v1.y};
        u0.h[3] = h2v{(h1)v1.z, (h1)v1.w};
        u1.h[0] = h2v{(h1)v2.x, (h1)v2.y};
        u1.h[1] = h2v{(h1)v2.z, (h1)v2.w};
        u1.h[2] = h2v{(h1)v3.x, (h1)v3.y};
        u1.h[3] = h2v{(h1)v3.z, (h1)v3.w};
        *(f4*)&xl[srow][c0 / 2]     = u0.v;
        *(f4*)&xl[srow][c0 / 2 + 4] = u1.v;
    }

    // ---- phase 1b: stage W slab [pair][k], sigmoid on the fly ----
    {
        const int kq = (t & 63) * 4;        // k_local quad (b128-aligned)
        const int p0 = (t >> 6) * 32;       // 32 pairs per wave-group
        const float* A0 = A + k0 + kq;
        #pragma unroll 4
        for (int pp = 0; pp < 32; ++pp) {
            const int p = p0 + pp;
            const f4 a0 = *(const f4*)&A0[(2 * p) * KD];       // coalesced 1KB/wave
            const f4 a1 = *(const f4*)&A0[(2 * p + 1) * KD];
            union { f4 v; h2v h[4]; } u;
            u.h[0] = h2v{(h1)sigmoidf_fast(a0.x), (h1)sigmoidf_fast(a1.x)};
            u.h[1] = h2v{(h1)sigmoidf_fast(a0.y), (h1)sigmoidf_fast(a1.y)};
            u.h[2] = h2v{(h1)sigmoidf_fast(a0.z), (h1)sigmoidf_fast(a1.z)};
            u.h[3] = h2v{(h1)sigmoidf_fast(a0.w), (h1)sigmoidf_fast(a1.w)};
            *(f4*)&Wl[p][kq] = u.v;         // full-row contiguous, conflict-free
        }
    }
    __syncthreads();

    // ---- phase 2: barrier-free ping-pong compute ----
    const int lane = t & 63;
    const int wv   = __builtin_amdgcn_readfirstlane(t >> 6);  // 0..3
    const int r0   = wv * TI;
    const int kq   = lane * 4;              // this lane's k quad

    h2v acc[TI][TK];
    #pragma unroll
    for (int r = 0; r < TI; ++r)
        #pragma unroll
        for (int s = 0; s < TK; ++s)
            acc[r][s] = h2v{(h1)(-65504.0f), (h1)(-65504.0f)};

    f4 XA[TI][2], XB[TI][2];    // per row: 8 pairs = 2 b128 (uniform)
    f4 WA[8], WB[8];            // per pair: lane's 4 k = 1 b128

    auto loadX = [&](f4 (&X)[TI][2], int c) {
        #pragma unroll
        for (int r = 0; r < TI; ++r) {
            X[r][0] = *(const f4*)&xl[r0 + r][c * 8];
            X[r][1] = *(const f4*)&xl[r0 + r][c * 8 + 4];
        }
    };
    auto loadW = [&](f4 (&W)[8], int c) {
        #pragma unroll
        for (int p = 0; p < 8; ++p)
            W[p] = *(const f4*)&Wl[c * 8 + p][kq];
    };
    auto compute = [&](const f4 (&X)[TI][2], const f4 (&W)[8]) {
        #pragma unroll
        for (int r = 0; r < TI; ++r) {
            union { f4 v; h2v h[4]; } ux0, ux1;
            ux0.v = X[r][0];
            ux1.v = X[r][1];
            #pragma unroll
            for (int p = 0; p < 8; ++p) {
                const h2v xp = (p < 4) ? ux0.h[p & 3] : ux1.h[p & 3];
                union { f4 v; h2v h[4]; } uw;
                uw.v = W[p];
                #pragma unroll
                for (int s = 0; s < TK; ++s)
                    acc[r][s] = __builtin_elementwise_max(acc[r][s],
                                                          xp * uw.h[s]);
            }
        }
    };

    loadX(XA, 0);
    loadW(WA, 0);

    #pragma unroll 1
    for (int c = 0; c < NCH; c += 2) {
        loadX(XB, c + 1);              // NCH even: c+1 always valid
        loadW(WB, c + 1);
        compute(XA, WA);
        if (c + 2 < NCH) {
            loadX(XA, c + 2);
            loadW(WA, c + 2);
        }
        compute(XB, WB);
    }

    // ---- epilogue: fold pair halves, coalesced float4 stores ----
    #pragma unroll
    for (int r = 0; r < TI; ++r) {
        f4 o;
        #pragma unroll
        for (int s = 0; s < TK; ++s)
            o[s] = fmaxf((float)acc[r][s][0], (float)acc[r][s][1]);
        *(f4*)&out[(i0 + r0 + r) * KD + k0 + kq] = o;
    }
}

extern "C" void kernel_launch(void* const* d_in, const int* in_sizes, int n_in,
                              void* d_out, int out_size, void* d_ws, size_t ws_size,
                              hipStream_t stream) {
    const float* x = (const float*)d_in[0];
    const float* A = (const float*)d_in[1];
    float* out = (float*)d_out;

    // 256 blocks: (i-block 0..127) x (k-slab 0..1); 4 waves x 4 rows each
    hipLaunchKernelGGL(tropical_fused, dim3(256), dim3(256), 0, stream,
                       x, A, out);
}

// Round 13
// 21.705 us; speedup vs baseline: 6.9588x; 1.3015x over previous
//
#include <hip/hip_runtime.h>

// Tropical (max-times) matmul: out[i,k] = max_j sigmoid(A[j,k]) * x[i,j]
// x: [2048, 256] f32   A: [256, 512] f32   out: [2048, 512] f32
//
// Round 13: no broadcasts anywhere (R10/R12 fits show broadcast b128 costs
// full 12cyc return BW), occupancy 4 waves/SIMD (R12 failed at 1/SIMD).
//  - x (wave-shared) -> SGPRs via s_load_dwordx8: 4B/value once, free pipe.
//    Per chunk only 32 SGPRs live (R2's capacity bug fixed). lgkm drain
//    covered by 16 waves/CU.
//  - W (lane-private) -> LDS quad-pair layout [p4][k] x 16B: lane reads
//    ds_read_b128 at 16B stride = conflict-free, 2 instr/chunk.
//  - wave = 4 rows x 64 k; block = 4 waves; LDS 32KB -> 4 blocks/CU.
//  - inner: v_pk_mul_f16 (SGPR x, VGPR w) + v_pk_max_f16.
//  - budgets/CU: VALU 8.2k cyc (3.4us), LDS 6.1k (2.6us), SMEM 2KB/wave.

typedef _Float16 h1;
typedef __attribute__((ext_vector_type(2))) _Float16 h2v;
typedef __attribute__((ext_vector_type(4))) float f4;
typedef __attribute__((ext_vector_type(4))) unsigned int u4;
typedef __attribute__((ext_vector_type(8))) unsigned int u8;

constexpr int JD = 256;
constexpr int KD = 512;

__device__ __forceinline__ float sigmoidf_fast(float a) {
    return 1.0f / (1.0f + __expf(-a));
}

__device__ __forceinline__ h2v asH2(unsigned int u) {
    union { unsigned int x; h2v h; } c; c.x = u; return c.h;
}

// Wq[p4*512 + k] (u4, 16B): q-th h2v = (sig A[8p4+2q][k], sig A[8p4+2q+1][k])
//   -> quad = j-pairs 4p4..4p4+3 for column k.  [32][512] x 16B = 256KB.
// xp[row*32 + g] (u4): 4 pairs (8 j) of row, fp16.  [2048][32] x 16B = 1MB.
__global__ __launch_bounds__(256) void prepack(const float* __restrict__ x,
                                               const float* __restrict__ A,
                                               u4* __restrict__ Wq,
                                               u4* __restrict__ xp4) {
    const int b = (int)blockIdx.x;
    if (b < 64) {   // W part: 16384 threads, one per (p4, k)
        const int t  = b * 256 + (int)threadIdx.x;
        const int p4 = t >> 9;                  // 0..31
        const int k  = t & 511;                 // coalesced across lanes
        union { u4 v; h2v h[4]; } u;
        #pragma unroll
        for (int q = 0; q < 4; ++q) {
            const float a0 = A[(8 * p4 + 2 * q) * KD + k];
            const float a1 = A[(8 * p4 + 2 * q + 1) * KD + k];
            u.h[q] = h2v{(h1)sigmoidf_fast(a0), (h1)sigmoidf_fast(a1)};
        }
        Wq[p4 * 512 + k] = u.v;
    } else {        // x part: 65536 threads, 8 floats -> 1 u4 each
        const int g = (b - 64) * 256 + (int)threadIdx.x;
        const f4 x0 = *(const f4*)&x[g * 8];
        const f4 x1 = *(const f4*)&x[g * 8 + 4];
        union { u4 v; h2v h[4]; } u;
        u.h[0] = h2v{(h1)x0.x, (h1)x0.y};
        u.h[1] = h2v{(h1)x0.z, (h1)x0.w};
        u.h[2] = h2v{(h1)x1.x, (h1)x1.y};
        u.h[3] = h2v{(h1)x1.z, (h1)x1.w};
        xp4[g] = u.v;
    }
}

__global__ __launch_bounds__(256) void tropical_main(
        const unsigned int* __restrict__ xp,   // dword view of xp4
        const u4* __restrict__ Wq,
        float* __restrict__ out) {
    __shared__ u4 Wl[32 * 64];   // [p4][k_local], 16B cells = 32KB

    const int t    = (int)threadIdx.x;
    const int lane = t & 63;
    const int wv   = __builtin_amdgcn_readfirstlane(t >> 6);   // 0..3
    const int kg   = (int)blockIdx.x & 7;      // 8 k-groups of 64
    const int rg   = (int)blockIdx.x >> 3;     // 128 row-groups of 16
    const int k0   = kg * 64;
    const int r0   = rg * 16 + wv * 4;         // this wave's 4 rows

    // ---- stage W slab (32 p4-rows x 64 k): wave reads 1KB contiguous per
    //      p4-row (global, coalesced), writes 16B-stride LDS (conflict-free)
    #pragma unroll
    for (int i = 0; i < 8; ++i) {
        const int p4 = wv * 8 + i;
        Wl[p4 * 64 + lane] = Wq[p4 * 512 + k0 + lane];
    }
    __syncthreads();

    const unsigned int* xr = xp + r0 * 128;    // 128 dwords per row (uniform)

    h2v acc[4];
    #pragma unroll
    for (int r = 0; r < 4; ++r)
        acc[r] = h2v{(h1)(-65504.0f), (h1)(-65504.0f)};

    // ---- main loop: 16 chunks of 8 pairs (16 j) ----
    #pragma unroll 2
    for (int c = 0; c < 16; ++c) {
        // x: 4 rows x 32B, uniform addresses -> s_load_dwordx8 each
        u8 X[4];
        #pragma unroll
        for (int r = 0; r < 4; ++r)
            X[r] = *(const u8*)(xr + r * 128 + c * 8);

        // W: 2 quad-pairs for this chunk, per-lane column, b128 16B-stride
        union { u4 v; h2v h[4]; } w0, w1;
        w0.v = Wl[(2 * c + 0) * 64 + lane];
        w1.v = Wl[(2 * c + 1) * 64 + lane];

        #pragma unroll
        for (int r = 0; r < 4; ++r) {
            #pragma unroll
            for (int q = 0; q < 4; ++q) {
                acc[r] = __builtin_elementwise_max(acc[r],
                                                   asH2(X[r][q]) * w0.h[q]);
                acc[r] = __builtin_elementwise_max(acc[r],
                                                   asH2(X[r][4 + q]) * w1.h[q]);
            }
        }
    }

    // ---- epilogue: fold pair halves, coalesced dword stores ----
    const int k = k0 + lane;
    #pragma unroll
    for (int r = 0; r < 4; ++r)
        out[(r0 + r) * KD + k] = fmaxf((float)acc[r][0], (float)acc[r][1]);
}

extern "C" void kernel_launch(void* const* d_in, const int* in_sizes, int n_in,
                              void* d_out, int out_size, void* d_ws, size_t ws_size,
                              hipStream_t stream) {
    const float* x = (const float*)d_in[0];
    const float* A = (const float*)d_in[1];
    float* out = (float*)d_out;

    u4* Wq  = (u4*)d_ws;                                 // 256 KB
    u4* xp4 = (u4*)((char*)d_ws + 256 * 1024);           // 1 MB

    hipLaunchKernelGGL(prepack, dim3(320), dim3(256), 0, stream, x, A, Wq, xp4);

    // 1024 blocks = (128 row-groups) x (8 k-groups); 4 blocks/CU, 16 waves/CU
    hipLaunchKernelGGL(tropical_main, dim3(1024), dim3(256), 0, stream,
                       (const unsigned int*)xp4, Wq, out);
}